// Round 1
// baseline (3956.694 us; speedup 1.0000x reference)
//
#include <hip/hip_runtime.h>

// EnhancedRGCN on MI355X — fp32 end-to-end (threshold ~2e-5 forbids bf16 matmul).
// Pipeline: degrees+CSR -> pre-FF (3 GEMMs, chunked) -> conv1 -> conv2 -> conv3
// -> post-FF. All aggregations are CSR gathers (no float atomics).

#define NT 300000
#define NC 100000
#define NM 20000
#define DIN 390
#define DD 128
#define DOUT 64
#define HPRE 256
#define HPOST 64

// ---------------------------------------------------------------------------
// Generic tiled fp32 GEMM: C[M,N] = act((A * rowscale[row]) @ W + bias)
// A: MxK row-major. W: KxN row-major, N % 64 == 0. C: MxN row-major.
// BM=BN=64, BK=16, 256 threads, 4x4 microtile per thread.
// ---------------------------------------------------------------------------
__global__ __launch_bounds__(256) void gemm_kernel(
    const float* __restrict__ A, const float* __restrict__ W,
    const float* __restrict__ bias, const float* __restrict__ rowscale,
    float* __restrict__ C, int M, int K, int N, int relu)
{
    __shared__ float As[16][68];  // transposed A tile: As[k][m], pad 68 (16B-aligned rows)
    __shared__ float Ws[16][68];  // W tile: Ws[k][n]

    const int bm = blockIdx.x * 64;
    const int bn = blockIdx.y * 64;
    const int tid = (int)threadIdx.x;
    const int tx = tid & 15;   // N direction (16)
    const int ty = tid >> 4;   // M direction (16)

    float acc[4][4] = {{0.f}};

    // staging roles
    const int ar  = tid >> 2;         // 0..63 : A row within tile
    const int ac4 = (tid & 3) << 2;   // 0,4,8,12 : A k-offset
    const int wr  = tid >> 4;         // 0..15 : W k-row
    const int wc4 = (tid & 15) << 2;  // 0..60 : W n-offset

    const int arow = bm + ar;
    float ascale = 1.0f;
    if (rowscale != nullptr && arow < M) ascale = rowscale[arow];

    for (int k0 = 0; k0 < K; k0 += 16) {
        // --- stage A (transposed into LDS), guarded on M and K tails ---
        float4 av = make_float4(0.f, 0.f, 0.f, 0.f);
        const int kb = k0 + ac4;
        if (arow < M) {
            const float* ap = A + (size_t)arow * K + kb;
            if (kb + 3 < K) {
                av = *(const float4*)ap;
            } else {
                av.x = (kb + 0 < K) ? ap[0] : 0.f;
                av.y = (kb + 1 < K) ? ap[1] : 0.f;
                av.z = (kb + 2 < K) ? ap[2] : 0.f;
                av.w = (kb + 3 < K) ? ap[3] : 0.f;
            }
        }
        As[ac4 + 0][ar] = av.x * ascale;
        As[ac4 + 1][ar] = av.y * ascale;
        As[ac4 + 2][ar] = av.z * ascale;
        As[ac4 + 3][ar] = av.w * ascale;

        // --- stage W (N multiple of 64 -> no column guard) ---
        float4 wv = make_float4(0.f, 0.f, 0.f, 0.f);
        const int krow = k0 + wr;
        if (krow < K) wv = *(const float4*)(W + (size_t)krow * N + bn + wc4);
        *(float4*)&Ws[wr][wc4] = wv;

        __syncthreads();

        #pragma unroll
        for (int kk = 0; kk < 16; ++kk) {
            float4 a4 = *(const float4*)&As[kk][ty << 2];
            float4 b4 = *(const float4*)&Ws[kk][tx << 2];
            float avv[4] = {a4.x, a4.y, a4.z, a4.w};
            float bvv[4] = {b4.x, b4.y, b4.z, b4.w};
            #pragma unroll
            for (int i = 0; i < 4; ++i)
                #pragma unroll
                for (int j = 0; j < 4; ++j)
                    acc[i][j] = fmaf(avv[i], bvv[j], acc[i][j]);
        }
        __syncthreads();
    }

    // --- epilogue: bias + relu, float4 stores ---
    #pragma unroll
    for (int i = 0; i < 4; ++i) {
        const int row = bm + (ty << 2) + i;
        if (row >= M) continue;
        const int col = bn + (tx << 2);
        float4 o;
        o.x = acc[i][0]; o.y = acc[i][1]; o.z = acc[i][2]; o.w = acc[i][3];
        if (bias != nullptr) {
            o.x += bias[col + 0]; o.y += bias[col + 1];
            o.z += bias[col + 2]; o.w += bias[col + 3];
        }
        if (relu) {
            o.x = fmaxf(o.x, 0.f); o.y = fmaxf(o.y, 0.f);
            o.z = fmaxf(o.z, 0.f); o.w = fmaxf(o.w, 0.f);
        }
        *(float4*)(C + (size_t)row * N + col) = o;
    }
}

// ---------------------------------------------------------------------------
// Graph helper kernels
// ---------------------------------------------------------------------------
__global__ void count_kernel(const int* __restrict__ card, const int* __restrict__ merch,
                             int* cnt_c, int* cnt_m, int n)
{
    int t = blockIdx.x * blockDim.x + threadIdx.x;
    if (t >= n) return;
    atomicAdd(&cnt_c[card[t]], 1);
    atomicAdd(&cnt_m[merch[t]], 1);
}

__global__ void rsqrt_kernel(const int* __restrict__ cnt, float* __restrict__ rs, int n)
{
    int i = blockIdx.x * blockDim.x + threadIdx.x;
    if (i >= n) return;
    int c = cnt[i];
    if (c < 1) c = 1;
    rs[i] = 1.0f / sqrtf((float)c);   // accurate path (not v_rsq approx)
}

// Exclusive scan, single block of 1024 threads, wave-shuffle based (2 barriers/chunk).
__global__ __launch_bounds__(1024) void scan_excl(const int* __restrict__ cnt,
                                                  int* __restrict__ off, int n)
{
    __shared__ int wsum[16];
    const int tid = (int)threadIdx.x;
    const int lane = tid & 63, wid = tid >> 6;
    int carry = 0;
    for (int base = 0; base < n; base += 1024) {
        int i = base + tid;
        int v = (i < n) ? cnt[i] : 0;
        int x = v;  // inclusive wave scan
        #pragma unroll
        for (int d = 1; d < 64; d <<= 1) {
            int y = __shfl_up(x, d);
            if (lane >= d) x += y;
        }
        if (lane == 63) wsum[wid] = x;
        __syncthreads();
        int wpre = 0, tot = 0;
        #pragma unroll
        for (int w = 0; w < 16; ++w) {
            int s = wsum[w];
            if (w < wid) wpre += s;
            tot += s;
        }
        if (i < n) off[i] = carry + wpre + (x - v);
        carry += tot;
        __syncthreads();
    }
    if (tid == 0) off[n] = carry;
}

__global__ void fill_sorted(const int* __restrict__ ids, const int* __restrict__ off,
                            int* cur, int* __restrict__ srt, int n)
{
    int t = blockIdx.x * blockDim.x + threadIdx.x;
    if (t >= n) return;
    int c = ids[t];
    int p = atomicAdd(&cur[c], 1);
    srt[off[c] + p] = t;
}

// h_t[t][:] = act(hc[card[t]][:] + hm[merch[t]][:] + b0 + b1); dim in {64,128}
__global__ void gather2_kernel(const float* __restrict__ hc, const float* __restrict__ hm,
                               const int* __restrict__ card, const int* __restrict__ merch,
                               const float* __restrict__ b0, const float* __restrict__ b1,
                               float* __restrict__ out, int n, int dim, int relu)
{
    int idx = blockIdx.x * blockDim.x + threadIdx.x;
    int per = dim >> 2;
    int t = idx / per;
    if (t >= n) return;
    int d4 = (idx % per) << 2;
    int c = card[t], m = merch[t];
    float4 a = *(const float4*)(hc + (size_t)c * dim + d4);
    float4 b = *(const float4*)(hm + (size_t)m * dim + d4);
    float4 v0 = *(const float4*)(b0 + d4);
    float4 v1 = *(const float4*)(b1 + d4);
    float4 r;
    r.x = a.x + b.x + v0.x + v1.x;
    r.y = a.y + b.y + v0.y + v1.y;
    r.z = a.z + b.z + v0.z + v1.z;
    r.w = a.w + b.w + v0.w + v1.w;
    if (relu) {
        r.x = fmaxf(r.x, 0.f); r.y = fmaxf(r.y, 0.f);
        r.z = fmaxf(r.z, 0.f); r.w = fmaxf(r.w, 0.f);
    }
    *(float4*)(out + (size_t)t * dim + d4) = r;
}

// out[node][:] = act( (sum over CSR list of proj[t][:]) * rs[node] + bias ), dim=128
__global__ __launch_bounds__(256) void agg_csr_kernel(
    const float* __restrict__ proj, const int* __restrict__ off,
    const int* __restrict__ srt, const float* __restrict__ rs,
    const float* __restrict__ bias, float* __restrict__ out, int n, int relu)
{
    int node = blockIdx.x * 2 + ((int)threadIdx.x >> 7);
    int d = (int)threadIdx.x & 127;
    if (node >= n) return;
    int s = off[node], e = off[node + 1];
    float acc = 0.f;
    for (int i = s; i < e; ++i) {
        int t = srt[i];
        acc += proj[(size_t)t * 128 + d];
    }
    float v = acc * rs[node] + bias[d];
    if (relu) v = fmaxf(v, 0.f);
    out[(size_t)node * 128 + d] = v;
}

// s2[t][0] = dot(h[t], w0), s2[t][1] = dot(h[t], w1); K=128, wave per row
__global__ __launch_bounds__(256) void dot2_kernel(
    const float* __restrict__ h, const float* __restrict__ w0,
    const float* __restrict__ w1, float* __restrict__ s2, int n)
{
    int row = blockIdx.x * 4 + ((int)threadIdx.x >> 6);
    int l = (int)threadIdx.x & 63;
    if (row >= n) return;
    const float* x = h + (size_t)row * 128;
    float x0 = x[l], x1 = x[l + 64];
    float p0 = x0 * w0[l] + x1 * w0[l + 64];
    float p1 = x0 * w1[l] + x1 * w1[l + 64];
    #pragma unroll
    for (int o = 32; o > 0; o >>= 1) {
        p0 += __shfl_down(p0, o);
        p1 += __shfl_down(p1, o);
    }
    if (l == 0) { s2[(size_t)row * 2] = p0; s2[(size_t)row * 2 + 1] = p1; }
}

// out[node] = (sum over CSR list of s2[t*2+which]) * rs[node] + bias[0]
__global__ void agg_scalar_kernel(const float* __restrict__ s2, int which,
                                  const int* __restrict__ off, const int* __restrict__ srt,
                                  const float* __restrict__ rs, const float* __restrict__ bias,
                                  float* __restrict__ out, int n)
{
    int node = blockIdx.x * blockDim.x + threadIdx.x;
    if (node >= n) return;
    float acc = 0.f;
    int e = off[node + 1];
    for (int i = off[node]; i < e; ++i) acc += s2[(size_t)srt[i] * 2 + which];
    out[node] = acc * rs[node] + bias[0];
}

// out[row] = dot(h[row], w) + b[0]; K=64, wave per row
__global__ __launch_bounds__(256) void dot1_kernel(
    const float* __restrict__ h, const float* __restrict__ w,
    const float* __restrict__ b, float* __restrict__ out, int n)
{
    int row = blockIdx.x * 4 + ((int)threadIdx.x >> 6);
    int l = (int)threadIdx.x & 63;
    if (row >= n) return;
    float p = h[(size_t)row * 64 + l] * w[l];
    #pragma unroll
    for (int o = 32; o > 0; o >>= 1) p += __shfl_down(p, o);
    if (l == 0) out[row] = p + b[0];
}

// ---------------------------------------------------------------------------
static inline void gemm(const float* A, const float* W, const float* bias,
                        const float* rowscale, float* C, int M, int K, int N,
                        int relu, hipStream_t s)
{
    dim3 grid((M + 63) / 64, N / 64);
    gemm_kernel<<<grid, 256, 0, s>>>(A, W, bias, rowscale, C, M, K, N, relu);
}

extern "C" void kernel_launch(void* const* d_in, const int* in_sizes, int n_in,
                              void* d_out, int out_size, void* d_ws, size_t ws_size,
                              hipStream_t stream)
{
    const float* x_in      = (const float*)d_in[0];
    const int*   card      = (const int*)d_in[1];
    const int*   merch     = (const int*)d_in[2];
    const float* card_emb  = (const float*)d_in[3];
    const float* merch_emb = (const float*)d_in[4];
    const float* pre_Wi = (const float*)d_in[5];
    const float* pre_bi = (const float*)d_in[6];
    const float* pre_Wh = (const float*)d_in[7];
    const float* pre_bh = (const float*)d_in[8];
    const float* pre_Wo = (const float*)d_in[9];
    const float* pre_bo = (const float*)d_in[10];
    const float* conv1_W = (const float*)d_in[11];
    const float* conv1_b = (const float*)d_in[12];
    const float* conv2_W = (const float*)d_in[13];
    const float* conv2_b = (const float*)d_in[14];
    const float* conv3_Wt = (const float*)d_in[15];
    const float* conv3_bt = (const float*)d_in[16];
    const float* conv3_Wo = (const float*)d_in[17];
    const float* conv3_bo = (const float*)d_in[18];
    const float* post_Wi = (const float*)d_in[19];
    const float* post_bi = (const float*)d_in[20];
    const float* post_Wh = (const float*)d_in[21];
    const float* post_bh = (const float*)d_in[22];
    const float* post_Wo = (const float*)d_in[23];
    const float* post_bo = (const float*)d_in[24];

    float* out = (float*)d_out;

    // ---- workspace carve (total ~960 MB) ----
    char* ws = (char*)d_ws;
    size_t off = 0;
    auto alloc = [&](size_t bytes) -> char* {
        char* p = ws + off;
        off += (bytes + 255) & ~(size_t)255;
        return p;
    };
    int* cnt_c = (int*)alloc((size_t)NC * 4);
    int* cnt_m = (int*)alloc((size_t)NM * 4);
    int* cur_c = (int*)alloc((size_t)NC * 4);
    int* cur_m = (int*)alloc((size_t)NM * 4);
    size_t zero_bytes = (size_t)((char*)(cur_m + NM) - (char*)cnt_c);
    int* off_c = (int*)alloc((size_t)(NC + 1) * 4);
    int* off_m = (int*)alloc((size_t)(NM + 1) * 4);
    int* srt_c = (int*)alloc((size_t)NT * 4);
    int* srt_m = (int*)alloc((size_t)NT * 4);
    float* rs_c = (float*)alloc((size_t)NC * 4);
    float* rs_m = (float*)alloc((size_t)NM * 4);
    const int MCH = 75000;  // pre-FF row chunk (4 chunks)
    float* bufA = (float*)alloc((size_t)MCH * HPRE * 4);
    float* bufB = (float*)alloc((size_t)MCH * HPRE * 4);
    float* tf   = (float*)alloc((size_t)NT * DD * 4);
    float* proj = (float*)alloc((size_t)NT * DD * 4);
    float* h1_t = (float*)alloc((size_t)NT * DD * 4);
    float* h2_t = (float*)alloc((size_t)NT * DD * 4);
    float* h1_c = (float*)alloc((size_t)NC * DD * 4);
    float* h2_c = (float*)alloc((size_t)NC * DD * 4);
    float* hc_p = (float*)alloc((size_t)NC * DD * 4);
    float* h1_m = (float*)alloc((size_t)NM * DD * 4);
    float* h2_m = (float*)alloc((size_t)NM * DD * 4);
    float* hm_p = (float*)alloc((size_t)NM * DD * 4);
    float* s2   = (float*)alloc((size_t)NT * 2 * 4);
    // aliases onto dead buffers:
    float* h3t64 = h1_t;                  // NT x 64 (h1_t dead after conv2)
    float* p1 = h2_t;                     // NT x 64 (h2_t dead after dot2)
    float* p2 = h2_t + (size_t)NT * 64;   // NT x 64
    (void)ws_size; (void)in_sizes; (void)n_in; (void)out_size;

    // ---- degrees + CSR ----
    hipMemsetAsync(cnt_c, 0, zero_bytes, stream);
    count_kernel<<<(NT + 255) / 256, 256, 0, stream>>>(card, merch, cnt_c, cnt_m, NT);
    rsqrt_kernel<<<(NC + 255) / 256, 256, 0, stream>>>(cnt_c, rs_c, NC);
    rsqrt_kernel<<<(NM + 255) / 256, 256, 0, stream>>>(cnt_m, rs_m, NM);
    scan_excl<<<1, 1024, 0, stream>>>(cnt_c, off_c, NC);
    scan_excl<<<1, 1024, 0, stream>>>(cnt_m, off_m, NM);
    fill_sorted<<<(NT + 255) / 256, 256, 0, stream>>>(card, off_c, cur_c, srt_c, NT);
    fill_sorted<<<(NT + 255) / 256, 256, 0, stream>>>(merch, off_m, cur_m, srt_m, NT);

    // ---- pre-FF: 390 -> 256 -> 256 -> 128, chunked over rows ----
    for (int c = 0; c < 4; ++c) {
        const float* xa = x_in + (size_t)c * MCH * DIN;
        gemm(xa,   pre_Wi, pre_bi, nullptr, bufA, MCH, DIN,  HPRE, 1, stream);
        gemm(bufA, pre_Wh, pre_bh, nullptr, bufB, MCH, HPRE, HPRE, 1, stream);
        gemm(bufB, pre_Wo, pre_bo, nullptr, tf + (size_t)c * MCH * DD, MCH, HPRE, DD, 0, stream);
    }

    // ---- conv1 ----
    gemm(card_emb,  conv1_W + 0 * DD * DD, nullptr, rs_c, hc_p, NC, DD, DD, 0, stream);
    gemm(merch_emb, conv1_W + 1 * DD * DD, nullptr, rs_m, hm_p, NM, DD, DD, 0, stream);
    gather2_kernel<<<(NT * (DD / 4) + 255) / 256, 256, 0, stream>>>(
        hc_p, hm_p, card, merch, conv1_b, conv1_b + DD, h1_t, NT, DD, 1);
    gemm(tf, conv1_W + 2 * DD * DD, nullptr, nullptr, proj, NT, DD, DD, 0, stream);
    agg_csr_kernel<<<(NC + 1) / 2, 256, 0, stream>>>(proj, off_c, srt_c, rs_c,
                                                     conv1_b + 2 * DD, h1_c, NC, 1);
    gemm(tf, conv1_W + 3 * DD * DD, nullptr, nullptr, proj, NT, DD, DD, 0, stream);
    agg_csr_kernel<<<(NM + 1) / 2, 256, 0, stream>>>(proj, off_m, srt_m, rs_m,
                                                     conv1_b + 3 * DD, h1_m, NM, 1);

    // ---- conv2 ----
    gemm(h1_c, conv2_W + 0 * DD * DD, nullptr, rs_c, hc_p, NC, DD, DD, 0, stream);
    gemm(h1_m, conv2_W + 1 * DD * DD, nullptr, rs_m, hm_p, NM, DD, DD, 0, stream);
    gather2_kernel<<<(NT * (DD / 4) + 255) / 256, 256, 0, stream>>>(
        hc_p, hm_p, card, merch, conv2_b, conv2_b + DD, h2_t, NT, DD, 1);
    gemm(h1_t, conv2_W + 2 * DD * DD, nullptr, nullptr, proj, NT, DD, DD, 0, stream);
    agg_csr_kernel<<<(NC + 1) / 2, 256, 0, stream>>>(proj, off_c, srt_c, rs_c,
                                                     conv2_b + 2 * DD, h2_c, NC, 1);
    gemm(h1_t, conv2_W + 3 * DD * DD, nullptr, nullptr, proj, NT, DD, DD, 0, stream);
    agg_csr_kernel<<<(NM + 1) / 2, 256, 0, stream>>>(proj, off_m, srt_m, rs_m,
                                                     conv2_b + 3 * DD, h2_m, NM, 1);

    // ---- conv3 ----
    gemm(h2_c, conv3_Wt + 0 * DD * DOUT, nullptr, rs_c, hc_p, NC, DD, DOUT, 0, stream);
    gemm(h2_m, conv3_Wt + 1 * DD * DOUT, nullptr, rs_m, hm_p, NM, DD, DOUT, 0, stream);
    gather2_kernel<<<(NT * (DOUT / 4) + 255) / 256, 256, 0, stream>>>(
        hc_p, hm_p, card, merch, conv3_bt, conv3_bt + DOUT, h3t64, NT, DOUT, 0);
    dot2_kernel<<<(NT + 3) / 4, 256, 0, stream>>>(h2_t, conv3_Wo, conv3_Wo + DD, s2, NT);
    agg_scalar_kernel<<<(NC + 255) / 256, 256, 0, stream>>>(s2, 0, off_c, srt_c, rs_c,
                                                            conv3_bo + 0, out + NT, NC);
    agg_scalar_kernel<<<(NM + 255) / 256, 256, 0, stream>>>(s2, 1, off_m, srt_m, rs_m,
                                                            conv3_bo + 1, out + NT + NC, NM);

    // ---- post-FF: 64 -> 64 -> 64 -> 1 ----
    gemm(h3t64, post_Wi, post_bi, nullptr, p1, NT, DOUT,  HPOST, 1, stream);
    gemm(p1,    post_Wh, post_bh, nullptr, p2, NT, HPOST, HPOST, 1, stream);
    dot1_kernel<<<(NT + 3) / 4, 256, 0, stream>>>(p2, post_Wo, post_bo, out, NT);
}

// Round 2
// 2912.269 us; speedup vs baseline: 1.3586x; 1.3586x over previous
//
#include <hip/hip_runtime.h>

// EnhancedRGCN on MI355X — split-f16 MFMA GEMMs (fp32-accurate via hi/lo
// decomposition, 3 MFMA terms), CSR-gather aggregations, fp32 elementwise.
//
// x = hi + lo/512, hi=f16(x), lo=f16((x-hi)*512)  [x512 keeps lo out of f16
// denormal range]. A@W = hiA@hiW + (hiA@loW + loA@hiW)/512; the two cross
// terms share one accumulator since both carry exactly x512.

#define NT 300000
#define NC 100000
#define NM 20000
#define DIN 390
#define DD 128
#define DOUT 64
#define HPRE 256
#define HPOST 64

typedef _Float16 half8 __attribute__((ext_vector_type(8)));
typedef float f32x16 __attribute__((ext_vector_type(16)));

#define LO_SCALE 512.0f
#define LO_INV   (1.0f / 512.0f)

__device__ __forceinline__ void split2(float x, _Float16& h, _Float16& l) {
    _Float16 hh = (_Float16)x;
    h = hh;
    l = (_Float16)((x - (float)hh) * LO_SCALE);
}

// ---------------------------------------------------------------------------
// Split-f16 MFMA GEMM: C[M,N] = act( (A @ W) * rowscale[row] + bias )
// A: MxK fp32 row-major. W: pre-split hi/lo f16 planes, TRANSPOSED [N][Kpad].
// BM = 32*TM*WGM = 128 always; BN = 32*TN*WGN (128 or 64). 256 threads.
// Wave tile = (32*TM) x (32*TN) of v_mfma_f32_32x32x16_f16 tiles.
// ---------------------------------------------------------------------------
template<int TM, int TN, int WGM, int WGN>
__global__ __launch_bounds__(256, 2) void gemm_mfma(
    const float* __restrict__ A, const _Float16* __restrict__ Wh,
    const _Float16* __restrict__ Wl, const float* __restrict__ bias,
    const float* __restrict__ rowscale, float* __restrict__ C,
    int M, int K, int N, int Kpad, int relu)
{
    constexpr int BM = 32 * TM * WGM;   // 128
    constexpr int BN = 32 * TN * WGN;   // 128 or 64
    constexpr int RS = 40;              // LDS row stride in halves (80 B, 16B-aligned)
    __shared__ __align__(16) _Float16 Ah[BM * RS];
    __shared__ __align__(16) _Float16 Al[BM * RS];
    __shared__ __align__(16) _Float16 Bh[BN * RS];
    __shared__ __align__(16) _Float16 Bl[BN * RS];

    const int tid  = (int)threadIdx.x;
    const int lane = tid & 63;
    const int wave = tid >> 6;
    const int wm0 = (wave % WGM) * 32 * TM;
    const int wn0 = (wave / WGM) * 32 * TN;
    const int bm = blockIdx.x * BM;
    const int bn = blockIdx.y * BN;

    f32x16 zz;
    #pragma unroll
    for (int i = 0; i < 16; ++i) zz[i] = 0.f;
    f32x16 acc_hh[TM][TN], acc_x[TM][TN];
    #pragma unroll
    for (int tm = 0; tm < TM; ++tm)
        #pragma unroll
        for (int tn = 0; tn < TN; ++tn) { acc_hh[tm][tn] = zz; acc_x[tm][tn] = zz; }

    // A staging role: 2 threads per row, 16 k-values each
    const int sar = tid >> 1;
    const int sak = (tid & 1) * 16;
    const int agrow = bm + sar;
    const float* Aptr = A + (size_t)agrow * K;

    const int ml  = lane & 31;          // MFMA m/n index
    const int klo = (lane >> 5) * 8;    // MFMA k sub-offset

    for (int k0 = 0; k0 < K; k0 += 32) {
        // ---- stage A: fp32 -> hi/lo f16 planes (guarded on M and K tails) ----
        {
            _Float16 hh[16], ll[16];
            #pragma unroll
            for (int q = 0; q < 4; ++q) {
                const int kb = k0 + sak + q * 4;
                float4 f = make_float4(0.f, 0.f, 0.f, 0.f);
                if (agrow < M) {
                    if (kb + 3 < K) {
                        f = *(const float4*)(Aptr + kb);
                    } else {
                        if (kb + 0 < K) f.x = Aptr[kb + 0];
                        if (kb + 1 < K) f.y = Aptr[kb + 1];
                        if (kb + 2 < K) f.z = Aptr[kb + 2];
                        if (kb + 3 < K) f.w = Aptr[kb + 3];
                    }
                }
                split2(f.x, hh[q * 4 + 0], ll[q * 4 + 0]);
                split2(f.y, hh[q * 4 + 1], ll[q * 4 + 1]);
                split2(f.z, hh[q * 4 + 2], ll[q * 4 + 2]);
                split2(f.w, hh[q * 4 + 3], ll[q * 4 + 3]);
            }
            half8 h0, h1, l0, l1;
            #pragma unroll
            for (int j = 0; j < 8; ++j) {
                h0[j] = hh[j]; h1[j] = hh[8 + j];
                l0[j] = ll[j]; l1[j] = ll[8 + j];
            }
            *(half8*)&Ah[sar * RS + sak]     = h0;
            *(half8*)&Ah[sar * RS + sak + 8] = h1;
            *(half8*)&Al[sar * RS + sak]     = l0;
            *(half8*)&Al[sar * RS + sak + 8] = l1;
        }
        // ---- stage W planes (pre-padded to Kpad, pre-transposed [N][Kpad]) ----
        if constexpr (BN == 128) {
            const int n = tid >> 1, kq = (tid & 1) * 16;
            const size_t g = (size_t)(bn + n) * Kpad + k0 + kq;
            *(half8*)&Bh[n * RS + kq]     = *(const half8*)(Wh + g);
            *(half8*)&Bh[n * RS + kq + 8] = *(const half8*)(Wh + g + 8);
            *(half8*)&Bl[n * RS + kq]     = *(const half8*)(Wl + g);
            *(half8*)&Bl[n * RS + kq + 8] = *(const half8*)(Wl + g + 8);
        } else {
            const int n = tid >> 2, kq = (tid & 3) * 8;
            const size_t g = (size_t)(bn + n) * Kpad + k0 + kq;
            *(half8*)&Bh[n * RS + kq] = *(const half8*)(Wh + g);
            *(half8*)&Bl[n * RS + kq] = *(const half8*)(Wl + g);
        }
        __syncthreads();

        #pragma unroll
        for (int ks = 0; ks < 2; ++ks) {
            const int kk = ks * 16 + klo;
            half8 fa_h[TM], fa_l[TM], fb_h[TN], fb_l[TN];
            #pragma unroll
            for (int t = 0; t < TM; ++t) {
                const int m = wm0 + t * 32 + ml;
                fa_h[t] = *(const half8*)&Ah[m * RS + kk];
                fa_l[t] = *(const half8*)&Al[m * RS + kk];
            }
            #pragma unroll
            for (int t = 0; t < TN; ++t) {
                const int n = wn0 + t * 32 + ml;
                fb_h[t] = *(const half8*)&Bh[n * RS + kk];
                fb_l[t] = *(const half8*)&Bl[n * RS + kk];
            }
            #pragma unroll
            for (int tm = 0; tm < TM; ++tm)
                #pragma unroll
                for (int tn = 0; tn < TN; ++tn) {
                    acc_hh[tm][tn] = __builtin_amdgcn_mfma_f32_32x32x16_f16(
                        fa_h[tm], fb_h[tn], acc_hh[tm][tn], 0, 0, 0);
                    acc_x[tm][tn] = __builtin_amdgcn_mfma_f32_32x32x16_f16(
                        fa_h[tm], fb_l[tn], acc_x[tm][tn], 0, 0, 0);
                    acc_x[tm][tn] = __builtin_amdgcn_mfma_f32_32x32x16_f16(
                        fa_l[tm], fb_h[tn], acc_x[tm][tn], 0, 0, 0);
                }
        }
        __syncthreads();
    }

    // ---- epilogue: combine accumulators, rowscale, bias, relu ----
    const int r0 = 4 * (lane >> 5);
    #pragma unroll
    for (int tm = 0; tm < TM; ++tm) {
        #pragma unroll
        for (int tn = 0; tn < TN; ++tn) {
            const int gcol = bn + wn0 + tn * 32 + ml;
            const float bc = (bias != nullptr) ? bias[gcol] : 0.f;
            #pragma unroll
            for (int r = 0; r < 16; ++r) {
                const int grow = bm + wm0 + tm * 32 + (r & 3) + r0 + 8 * (r >> 2);
                if (grow < M) {
                    float v = acc_hh[tm][tn][r] + acc_x[tm][tn][r] * LO_INV;
                    if (rowscale != nullptr) v *= rowscale[grow];
                    v += bc;
                    if (relu) v = fmaxf(v, 0.f);
                    C[(size_t)grow * N + gcol] = v;
                }
            }
        }
    }
}

// W[e][k][n] fp32 -> hiT/loT [e][n][Kpad] f16 planes (zero-padded K -> Kpad)
__global__ void split_w(const float* __restrict__ W, _Float16* __restrict__ hiT,
                        _Float16* __restrict__ loT, int K, int N, int Kpad, int nmat)
{
    int idx = blockIdx.x * blockDim.x + threadIdx.x;
    int total = nmat * N * Kpad;
    if (idx >= total) return;
    int e = idx / (N * Kpad);
    int rem = idx - e * (N * Kpad);
    int n = rem / Kpad;
    int k = rem - n * Kpad;
    float v = (k < K) ? W[((size_t)e * K + k) * N + n] : 0.f;
    _Float16 h = (_Float16)v;
    hiT[idx] = h;
    loT[idx] = (_Float16)((v - (float)h) * LO_SCALE);
}

// ---------------------------------------------------------------------------
// Graph helper kernels (unchanged from round 1, all fp32)
// ---------------------------------------------------------------------------
__global__ void count_kernel(const int* __restrict__ card, const int* __restrict__ merch,
                             int* cnt_c, int* cnt_m, int n)
{
    int t = blockIdx.x * blockDim.x + threadIdx.x;
    if (t >= n) return;
    atomicAdd(&cnt_c[card[t]], 1);
    atomicAdd(&cnt_m[merch[t]], 1);
}

__global__ void rsqrt_kernel(const int* __restrict__ cnt, float* __restrict__ rs, int n)
{
    int i = blockIdx.x * blockDim.x + threadIdx.x;
    if (i >= n) return;
    int c = cnt[i];
    if (c < 1) c = 1;
    rs[i] = 1.0f / sqrtf((float)c);
}

__global__ __launch_bounds__(1024) void scan_excl(const int* __restrict__ cnt,
                                                  int* __restrict__ off, int n)
{
    __shared__ int wsum[16];
    const int tid = (int)threadIdx.x;
    const int lane = tid & 63, wid = tid >> 6;
    int carry = 0;
    for (int base = 0; base < n; base += 1024) {
        int i = base + tid;
        int v = (i < n) ? cnt[i] : 0;
        int x = v;
        #pragma unroll
        for (int d = 1; d < 64; d <<= 1) {
            int y = __shfl_up(x, d);
            if (lane >= d) x += y;
        }
        if (lane == 63) wsum[wid] = x;
        __syncthreads();
        int wpre = 0, tot = 0;
        #pragma unroll
        for (int w = 0; w < 16; ++w) {
            int s = wsum[w];
            if (w < wid) wpre += s;
            tot += s;
        }
        if (i < n) off[i] = carry + wpre + (x - v);
        carry += tot;
        __syncthreads();
    }
    if (tid == 0) off[n] = carry;
}

__global__ void fill_sorted(const int* __restrict__ ids, const int* __restrict__ off,
                            int* cur, int* __restrict__ srt, int n)
{
    int t = blockIdx.x * blockDim.x + threadIdx.x;
    if (t >= n) return;
    int c = ids[t];
    int p = atomicAdd(&cur[c], 1);
    srt[off[c] + p] = t;
}

__global__ void gather2_kernel(const float* __restrict__ hc, const float* __restrict__ hm,
                               const int* __restrict__ card, const int* __restrict__ merch,
                               const float* __restrict__ b0, const float* __restrict__ b1,
                               float* __restrict__ out, int n, int dim, int relu)
{
    int idx = blockIdx.x * blockDim.x + threadIdx.x;
    int per = dim >> 2;
    int t = idx / per;
    if (t >= n) return;
    int d4 = (idx % per) << 2;
    int c = card[t], m = merch[t];
    float4 a = *(const float4*)(hc + (size_t)c * dim + d4);
    float4 b = *(const float4*)(hm + (size_t)m * dim + d4);
    float4 v0 = *(const float4*)(b0 + d4);
    float4 v1 = *(const float4*)(b1 + d4);
    float4 r;
    r.x = a.x + b.x + v0.x + v1.x;
    r.y = a.y + b.y + v0.y + v1.y;
    r.z = a.z + b.z + v0.z + v1.z;
    r.w = a.w + b.w + v0.w + v1.w;
    if (relu) {
        r.x = fmaxf(r.x, 0.f); r.y = fmaxf(r.y, 0.f);
        r.z = fmaxf(r.z, 0.f); r.w = fmaxf(r.w, 0.f);
    }
    *(float4*)(out + (size_t)t * dim + d4) = r;
}

__global__ __launch_bounds__(256) void agg_csr_kernel(
    const float* __restrict__ proj, const int* __restrict__ off,
    const int* __restrict__ srt, const float* __restrict__ rs,
    const float* __restrict__ bias, float* __restrict__ out, int n, int relu)
{
    int node = blockIdx.x * 2 + ((int)threadIdx.x >> 7);
    int d = (int)threadIdx.x & 127;
    if (node >= n) return;
    int s = off[node], e = off[node + 1];
    float acc = 0.f;
    for (int i = s; i < e; ++i) {
        int t = srt[i];
        acc += proj[(size_t)t * 128 + d];
    }
    float v = acc * rs[node] + bias[d];
    if (relu) v = fmaxf(v, 0.f);
    out[(size_t)node * 128 + d] = v;
}

__global__ __launch_bounds__(256) void dot2_kernel(
    const float* __restrict__ h, const float* __restrict__ w0,
    const float* __restrict__ w1, float* __restrict__ s2, int n)
{
    int row = blockIdx.x * 4 + ((int)threadIdx.x >> 6);
    int l = (int)threadIdx.x & 63;
    if (row >= n) return;
    const float* x = h + (size_t)row * 128;
    float x0 = x[l], x1 = x[l + 64];
    float p0 = x0 * w0[l] + x1 * w0[l + 64];
    float p1 = x0 * w1[l] + x1 * w1[l + 64];
    #pragma unroll
    for (int o = 32; o > 0; o >>= 1) {
        p0 += __shfl_down(p0, o);
        p1 += __shfl_down(p1, o);
    }
    if (l == 0) { s2[(size_t)row * 2] = p0; s2[(size_t)row * 2 + 1] = p1; }
}

__global__ void agg_scalar_kernel(const float* __restrict__ s2, int which,
                                  const int* __restrict__ off, const int* __restrict__ srt,
                                  const float* __restrict__ rs, const float* __restrict__ bias,
                                  float* __restrict__ out, int n)
{
    int node = blockIdx.x * blockDim.x + threadIdx.x;
    if (node >= n) return;
    float acc = 0.f;
    int e = off[node + 1];
    for (int i = off[node]; i < e; ++i) acc += s2[(size_t)srt[i] * 2 + which];
    out[node] = acc * rs[node] + bias[0];
}

__global__ __launch_bounds__(256) void dot1_kernel(
    const float* __restrict__ h, const float* __restrict__ w,
    const float* __restrict__ b, float* __restrict__ out, int n)
{
    int row = blockIdx.x * 4 + ((int)threadIdx.x >> 6);
    int l = (int)threadIdx.x & 63;
    if (row >= n) return;
    float p = h[(size_t)row * 64 + l] * w[l];
    #pragma unroll
    for (int o = 32; o > 0; o >>= 1) p += __shfl_down(p, o);
    if (l == 0) out[row] = p + b[0];
}

// ---------------------------------------------------------------------------
static inline void gemm128(const float* A, const _Float16* wh, const _Float16* wl,
                           const float* bias, const float* rs, float* C,
                           int M, int K, int N, int Kpad, int relu, hipStream_t s)
{
    dim3 grid((M + 127) / 128, N / 128);
    gemm_mfma<2, 2, 2, 2><<<grid, 256, 0, s>>>(A, wh, wl, bias, rs, C, M, K, N, Kpad, relu);
}

static inline void gemm64(const float* A, const _Float16* wh, const _Float16* wl,
                          const float* bias, const float* rs, float* C,
                          int M, int K, int N, int Kpad, int relu, hipStream_t s)
{
    dim3 grid((M + 127) / 128, N / 64);
    gemm_mfma<1, 2, 4, 1><<<grid, 256, 0, s>>>(A, wh, wl, bias, rs, C, M, K, N, Kpad, relu);
}

extern "C" void kernel_launch(void* const* d_in, const int* in_sizes, int n_in,
                              void* d_out, int out_size, void* d_ws, size_t ws_size,
                              hipStream_t stream)
{
    const float* x_in      = (const float*)d_in[0];
    const int*   card      = (const int*)d_in[1];
    const int*   merch     = (const int*)d_in[2];
    const float* card_emb  = (const float*)d_in[3];
    const float* merch_emb = (const float*)d_in[4];
    const float* pre_Wi = (const float*)d_in[5];
    const float* pre_bi = (const float*)d_in[6];
    const float* pre_Wh = (const float*)d_in[7];
    const float* pre_bh = (const float*)d_in[8];
    const float* pre_Wo = (const float*)d_in[9];
    const float* pre_bo = (const float*)d_in[10];
    const float* conv1_W = (const float*)d_in[11];
    const float* conv1_b = (const float*)d_in[12];
    const float* conv2_W = (const float*)d_in[13];
    const float* conv2_b = (const float*)d_in[14];
    const float* conv3_Wt = (const float*)d_in[15];
    const float* conv3_bt = (const float*)d_in[16];
    const float* conv3_Wo = (const float*)d_in[17];
    const float* conv3_bo = (const float*)d_in[18];
    const float* post_Wi = (const float*)d_in[19];
    const float* post_bi = (const float*)d_in[20];
    const float* post_Wh = (const float*)d_in[21];
    const float* post_bh = (const float*)d_in[22];
    const float* post_Wo = (const float*)d_in[23];
    const float* post_bo = (const float*)d_in[24];

    float* out = (float*)d_out;

    // ---- workspace carve (~1.37 GB of 1.87 GB) ----
    char* ws = (char*)d_ws;
    size_t off = 0;
    auto alloc = [&](size_t bytes) -> char* {
        char* p = ws + off;
        off += (bytes + 255) & ~(size_t)255;
        return p;
    };
    int* cnt_c = (int*)alloc((size_t)NC * 4);
    int* cnt_m = (int*)alloc((size_t)NM * 4);
    int* cur_c = (int*)alloc((size_t)NC * 4);
    int* cur_m = (int*)alloc((size_t)NM * 4);
    size_t zero_bytes = (size_t)((char*)(cur_m + NM) - (char*)cnt_c);
    int* off_c = (int*)alloc((size_t)(NC + 1) * 4);
    int* off_m = (int*)alloc((size_t)(NM + 1) * 4);
    int* srt_c = (int*)alloc((size_t)NT * 4);
    int* srt_m = (int*)alloc((size_t)NT * 4);
    float* rs_c = (float*)alloc((size_t)NC * 4);
    float* rs_m = (float*)alloc((size_t)NM * 4);

    // split-f16 weight planes, transposed [N][Kpad]
    const int KP_WI = 416;  // ceil32(390)
    _Float16* wi_h  = (_Float16*)alloc((size_t)HPRE * KP_WI * 2);
    _Float16* wi_l  = (_Float16*)alloc((size_t)HPRE * KP_WI * 2);
    _Float16* wh_h  = (_Float16*)alloc((size_t)HPRE * HPRE * 2);
    _Float16* wh_l  = (_Float16*)alloc((size_t)HPRE * HPRE * 2);
    _Float16* wo_h  = (_Float16*)alloc((size_t)DD * HPRE * 2);
    _Float16* wo_l  = (_Float16*)alloc((size_t)DD * HPRE * 2);
    _Float16* c1_h  = (_Float16*)alloc((size_t)4 * DD * DD * 2);
    _Float16* c1_l  = (_Float16*)alloc((size_t)4 * DD * DD * 2);
    _Float16* c2_h  = (_Float16*)alloc((size_t)4 * DD * DD * 2);
    _Float16* c2_l  = (_Float16*)alloc((size_t)4 * DD * DD * 2);
    _Float16* c3_h  = (_Float16*)alloc((size_t)2 * DOUT * DD * 2);
    _Float16* c3_l  = (_Float16*)alloc((size_t)2 * DOUT * DD * 2);
    _Float16* pi_h  = (_Float16*)alloc((size_t)HPOST * DOUT * 2);
    _Float16* pi_l  = (_Float16*)alloc((size_t)HPOST * DOUT * 2);
    _Float16* ph_h  = (_Float16*)alloc((size_t)HPOST * HPOST * 2);
    _Float16* ph_l  = (_Float16*)alloc((size_t)HPOST * HPOST * 2);

    float* bufA = (float*)alloc((size_t)NT * HPRE * 4);
    float* bufB = (float*)alloc((size_t)NT * HPRE * 4);
    float* tf   = (float*)alloc((size_t)NT * DD * 4);
    float* proj = (float*)alloc((size_t)NT * DD * 4);
    float* h1_t = (float*)alloc((size_t)NT * DD * 4);
    float* h2_t = (float*)alloc((size_t)NT * DD * 4);
    float* h1_c = (float*)alloc((size_t)NC * DD * 4);
    float* h2_c = (float*)alloc((size_t)NC * DD * 4);
    float* hc_p = (float*)alloc((size_t)NC * DD * 4);
    float* h1_m = (float*)alloc((size_t)NM * DD * 4);
    float* h2_m = (float*)alloc((size_t)NM * DD * 4);
    float* hm_p = (float*)alloc((size_t)NM * DD * 4);
    float* s2   = (float*)alloc((size_t)NT * 2 * 4);
    float* h3t64 = h1_t;                  // NT x 64 (h1_t dead after conv2)
    float* p1 = h2_t;                     // NT x 64 (h2_t dead after dot2)
    float* p2 = h2_t + (size_t)NT * 64;   // NT x 64
    (void)ws_size; (void)in_sizes; (void)n_in; (void)out_size;

    // ---- degrees + CSR ----
    hipMemsetAsync(cnt_c, 0, zero_bytes, stream);
    count_kernel<<<(NT + 255) / 256, 256, 0, stream>>>(card, merch, cnt_c, cnt_m, NT);
    rsqrt_kernel<<<(NC + 255) / 256, 256, 0, stream>>>(cnt_c, rs_c, NC);
    rsqrt_kernel<<<(NM + 255) / 256, 256, 0, stream>>>(cnt_m, rs_m, NM);
    scan_excl<<<1, 1024, 0, stream>>>(cnt_c, off_c, NC);
    scan_excl<<<1, 1024, 0, stream>>>(cnt_m, off_m, NM);
    fill_sorted<<<(NT + 255) / 256, 256, 0, stream>>>(card, off_c, cur_c, srt_c, NT);
    fill_sorted<<<(NT + 255) / 256, 256, 0, stream>>>(merch, off_m, cur_m, srt_m, NT);

    // ---- split + transpose weights into f16 hi/lo planes ----
    auto splitw = [&](const float* W, _Float16* h, _Float16* l, int K, int N, int Kpad, int nmat) {
        int total = nmat * N * Kpad;
        split_w<<<(total + 255) / 256, 256, 0, stream>>>(W, h, l, K, N, Kpad, nmat);
    };
    splitw(pre_Wi,   wi_h, wi_l, DIN,  HPRE,  KP_WI, 1);
    splitw(pre_Wh,   wh_h, wh_l, HPRE, HPRE,  HPRE,  1);
    splitw(pre_Wo,   wo_h, wo_l, HPRE, DD,    HPRE,  1);
    splitw(conv1_W,  c1_h, c1_l, DD,   DD,    DD,    4);
    splitw(conv2_W,  c2_h, c2_l, DD,   DD,    DD,    4);
    splitw(conv3_Wt, c3_h, c3_l, DD,   DOUT,  DD,    2);
    splitw(post_Wi,  pi_h, pi_l, DOUT, HPOST, DOUT,  1);
    splitw(post_Wh,  ph_h, ph_l, HPOST,HPOST, HPOST, 1);

    const int WP = DD * DD;  // per-etype plane size (halves)

    // ---- pre-FF: 390 -> 256 -> 256 -> 128 ----
    gemm128(x_in, wi_h, wi_l, pre_bi, nullptr, bufA, NT, DIN,  HPRE, KP_WI, 1, stream);
    gemm128(bufA, wh_h, wh_l, pre_bh, nullptr, bufB, NT, HPRE, HPRE, HPRE,  1, stream);
    gemm128(bufB, wo_h, wo_l, pre_bo, nullptr, tf,   NT, HPRE, DD,   HPRE,  0, stream);

    // ---- conv1 ----
    gemm128(card_emb,  c1_h + 0 * WP, c1_l + 0 * WP, nullptr, rs_c, hc_p, NC, DD, DD, DD, 0, stream);
    gemm128(merch_emb, c1_h + 1 * WP, c1_l + 1 * WP, nullptr, rs_m, hm_p, NM, DD, DD, DD, 0, stream);
    gather2_kernel<<<(NT * (DD / 4) + 255) / 256, 256, 0, stream>>>(
        hc_p, hm_p, card, merch, conv1_b, conv1_b + DD, h1_t, NT, DD, 1);
    gemm128(tf, c1_h + 2 * WP, c1_l + 2 * WP, nullptr, nullptr, proj, NT, DD, DD, DD, 0, stream);
    agg_csr_kernel<<<(NC + 1) / 2, 256, 0, stream>>>(proj, off_c, srt_c, rs_c,
                                                     conv1_b + 2 * DD, h1_c, NC, 1);
    gemm128(tf, c1_h + 3 * WP, c1_l + 3 * WP, nullptr, nullptr, proj, NT, DD, DD, DD, 0, stream);
    agg_csr_kernel<<<(NM + 1) / 2, 256, 0, stream>>>(proj, off_m, srt_m, rs_m,
                                                     conv1_b + 3 * DD, h1_m, NM, 1);

    // ---- conv2 ----
    gemm128(h1_c, c2_h + 0 * WP, c2_l + 0 * WP, nullptr, rs_c, hc_p, NC, DD, DD, DD, 0, stream);
    gemm128(h1_m, c2_h + 1 * WP, c2_l + 1 * WP, nullptr, rs_m, hm_p, NM, DD, DD, DD, 0, stream);
    gather2_kernel<<<(NT * (DD / 4) + 255) / 256, 256, 0, stream>>>(
        hc_p, hm_p, card, merch, conv2_b, conv2_b + DD, h2_t, NT, DD, 1);
    gemm128(h1_t, c2_h + 2 * WP, c2_l + 2 * WP, nullptr, nullptr, proj, NT, DD, DD, DD, 0, stream);
    agg_csr_kernel<<<(NC + 1) / 2, 256, 0, stream>>>(proj, off_c, srt_c, rs_c,
                                                     conv2_b + 2 * DD, h2_c, NC, 1);
    gemm128(h1_t, c2_h + 3 * WP, c2_l + 3 * WP, nullptr, nullptr, proj, NT, DD, DD, DD, 0, stream);
    agg_csr_kernel<<<(NM + 1) / 2, 256, 0, stream>>>(proj, off_m, srt_m, rs_m,
                                                     conv2_b + 3 * DD, h2_m, NM, 1);

    // ---- conv3 ----
    const int WP3 = DOUT * DD;
    gemm64(h2_c, c3_h + 0 * WP3, c3_l + 0 * WP3, nullptr, rs_c, hc_p, NC, DD, DOUT, DD, 0, stream);
    gemm64(h2_m, c3_h + 1 * WP3, c3_l + 1 * WP3, nullptr, rs_m, hm_p, NM, DD, DOUT, DD, 0, stream);
    gather2_kernel<<<(NT * (DOUT / 4) + 255) / 256, 256, 0, stream>>>(
        hc_p, hm_p, card, merch, conv3_bt, conv3_bt + DOUT, h3t64, NT, DOUT, 0);
    dot2_kernel<<<(NT + 3) / 4, 256, 0, stream>>>(h2_t, conv3_Wo, conv3_Wo + DD, s2, NT);
    agg_scalar_kernel<<<(NC + 255) / 256, 256, 0, stream>>>(s2, 0, off_c, srt_c, rs_c,
                                                            conv3_bo + 0, out + NT, NC);
    agg_scalar_kernel<<<(NM + 255) / 256, 256, 0, stream>>>(s2, 1, off_m, srt_m, rs_m,
                                                            conv3_bo + 1, out + NT + NC, NM);

    // ---- post-FF: 64 -> 64 -> 64 -> 1 ----
    gemm64(h3t64, pi_h, pi_l, post_bi, nullptr, p1, NT, DOUT,  HPOST, DOUT,  1, stream);
    gemm64(p1,    ph_h, ph_l, post_bh, nullptr, p2, NT, HPOST, HPOST, HPOST, 1, stream);
    dot1_kernel<<<(NT + 3) / 4, 256, 0, stream>>>(p2, post_Wo, post_bo, out, NT);
}